// Round 10
// baseline (159.003 us; speedup 1.0000x reference)
//
#include <hip/hip_runtime.h>
#include <hip/hip_bf16.h>
#include <stdint.h>

// HybridAttention: out = (softmax(scale*QK^T) + softmax_local(scale*QK^T)) @ V
// B=4, L=2048, H=8, E=64, fp32 in/out. Local window: j in [i-2, i+1] clamped.
//
// R10: barrier-free K-loop. Prepack writes K and V^T tiles FRAGMENT-MAJOR:
// fragment (n,f,lane) = 16 contiguous bytes at tile offset ((2n+f)*64+lane)*16.
// Each wave global_load_dwordx4's its MFMA fragments directly into registers
// (perfectly coalesced, 1KB/instr) — no LDS staging, no global_load_lds, no
// __syncthreads in the K-loop. Only sync: wave-local lgkmcnt for the Pt
// (C-layout -> B-operand) transform, proven since R3. Compute + epilogue are
// R9-verbatim. This removes the barrier-drain (~55% idle in R9) and the whole
// global_load_lds hazard class (R4/R6/R8 failures).

#define LQ 2048
#define HQ 8
#define EQ 64
#define BQ 4
#define BN 64
#define RS (HQ * EQ)                      // 512 floats between seq positions
#define SCALE_LOG2E 0.18033688011112042f  // 0.125 * log2(e)
#define NTILE (LQ / BN)                   // 32 key-tiles per (b,h)
#define TILE_U32 2048                     // 64x64 bf16 tile = 8 KB = 2048 u32
#define IMG_U32 (BQ * HQ * NTILE * TILE_U32)
#define BMQ 128                           // queries per block

typedef __attribute__((ext_vector_type(8))) short bf16x8;
typedef __attribute__((ext_vector_type(4))) float f32x4;
typedef __attribute__((ext_vector_type(4))) unsigned int u32x4;
typedef __attribute__((ext_vector_type(2))) unsigned int u32x2;

static __device__ __forceinline__ unsigned int f2bf(float f) {
    union { float f; unsigned int u; } c; c.f = f;
    return (c.u + 0x8000u) >> 16;
}
static __device__ __forceinline__ unsigned int pk2(float lo, float hi) {
    union { float f; unsigned int u; } a, b; a.f = lo; b.f = hi;
    return ((a.u + 0x8000u) >> 16) | ((b.u + 0x8000u) & 0xffff0000u);
}
static __device__ __forceinline__ float fexp2(float x) {
    float r;
    asm volatile("v_exp_f32 %0, %1\n\ts_nop 1" : "=v"(r) : "v"(x));
    return r;
}

// ---- pre-pass: K and V^T -> bf16 tiles in FRAGMENT-MAJOR layout.
// Tile (64 keys): u32x4 slot i (i=0..511) holds fragment (n=i>>7, f=(i>>6)&1,
// g=(i>>4)&3, c=i&15) = T[n*16+c][f*32+g*8 .. +7] where T = K rows (K image)
// or V^T rows (V image). Both phases coalesced; LDS transpose in between.
__global__ __launch_bounds__(256) void prepack_kernel(
    const float* __restrict__ K, const float* __restrict__ V,
    uint32_t* __restrict__ Kimg, uint32_t* __restrict__ Vimg)
{
    __shared__ unsigned short ts[64 * 72];  // plain [row][col] bf16, stride 72

    const int tid = threadIdx.x;
    const int jc  = blockIdx.x;
    const int bh  = blockIdx.y;
    const int b   = bh >> 3;
    const int h   = bh & 7;
    const int j0  = jc * BN;
    const float* Kbh = K + (size_t)b * LQ * RS + h * EQ;
    const float* Vbh = V + (size_t)b * LQ * RS + h * EQ;
    uint32_t* Kt = Kimg + (size_t)(bh * NTILE + jc) * TILE_U32;
    uint32_t* Vt = Vimg + (size_t)(bh * NTILE + jc) * TILE_U32;

    // K phase A: coalesced row reads -> LDS plain [j][k]
    #pragma unroll
    for (int it = 0; it < 2; ++it) {
        int t2 = tid + it * 256;
        int jr = t2 >> 3, eo = t2 & 7;
        const float* src = Kbh + (size_t)(j0 + jr) * RS + eo * 8;
        float4 a  = *(const float4*)src;
        float4 bv = *(const float4*)(src + 4);
        u32x4 p;
        p.x = pk2(a.x, a.y);   p.y = pk2(a.z, a.w);
        p.z = pk2(bv.x, bv.y); p.w = pk2(bv.z, bv.w);
        *(u32x4*)&ts[jr * 72 + eo * 8] = p;
    }
    __syncthreads();
    // K phase B: fragment-major coalesced global writes
    #pragma unroll
    for (int it = 0; it < 2; ++it) {
        int i = tid + it * 256;
        int n = i >> 7, f = (i >> 6) & 1, g = (i >> 4) & 3, c = i & 15;
        u32x4 p = *(const u32x4*)&ts[(n * 16 + c) * 72 + f * 32 + g * 8];
        *(u32x4*)&Kt[(size_t)i * 4] = p;
    }
    __syncthreads();

    // V phase A: coalesced row reads -> LDS transpose [e][j] (R7-proven)
    {
        const int jr = tid >> 2;          // 0..63
        const int e0 = (tid & 3) * 16;    // 0,16,32,48
        const float* src = Vbh + (size_t)(j0 + jr) * RS + e0;
        #pragma unroll
        for (int q = 0; q < 4; ++q) {
            float4 a = *(const float4*)(src + q * 4);
            const int e = e0 + q * 4;
            ts[(e + 0) * 72 + jr] = (unsigned short)f2bf(a.x);
            ts[(e + 1) * 72 + jr] = (unsigned short)f2bf(a.y);
            ts[(e + 2) * 72 + jr] = (unsigned short)f2bf(a.z);
            ts[(e + 3) * 72 + jr] = (unsigned short)f2bf(a.w);
        }
    }
    __syncthreads();
    // V phase B: fragment-major coalesced global writes
    #pragma unroll
    for (int it = 0; it < 2; ++it) {
        int i = tid + it * 256;
        int eg = i >> 7, f = (i >> 6) & 1, g = (i >> 4) & 3, c = i & 15;
        u32x4 p = *(const u32x4*)&ts[(eg * 16 + c) * 72 + f * 32 + g * 8];
        *(u32x4*)&Vt[(size_t)i * 4] = p;
    }
}

// ---- main attention kernel: 256 threads (4 waves), 128 queries/block,
// ---- 32 queries/wave as two 16-row q-tiles; NO barriers in the K-loop
__global__ __launch_bounds__(256) void hybrid_attn_v10(
    const float* __restrict__ Q, const float* __restrict__ K,
    const float* __restrict__ V, const uint32_t* __restrict__ Kimg,
    const uint32_t* __restrict__ Vimg, float* __restrict__ O)
{
    __shared__ unsigned short Pt[4][2048];  // per-wave P^T, per-t at t*1024
    __shared__ float sloc[BMQ][4];

    const int tid  = threadIdx.x;
    const int wave = tid >> 6;
    const int lane = tid & 63;
    const int c    = lane & 15;
    const int g    = lane >> 4;
    // XCD swizzle: xcd = linear_id % 8; give each XCD 4 bh's. grid = 512.
    const int id   = blockIdx.x;            // 0..511
    const int bh   = (id & 7) * 4 + ((id >> 3) & 3);
    const int qt   = id >> 5;               // 0..15
    const int b    = bh >> 3;
    const int h    = bh & 7;
    const int i0   = qt * BMQ;
    const int c7   = c & 7;
    const int sw3  = c7 << 1;   // Pt swizzle: bits 1-3 of the 8B-unit index

    const float* Qbh = Q + (size_t)b * LQ * RS + h * EQ;
    const float* Kbh = K + (size_t)b * LQ * RS + h * EQ;
    const float* Vbh = V + (size_t)b * LQ * RS + h * EQ;
    float*       Obh = O + (size_t)b * LQ * RS + h * EQ;

    // Q as B-operand fragments: 2 q-tiles x 2 k-halves, scale*log2e folded in
    bf16x8 qf[2][2];
    #pragma unroll
    for (int t = 0; t < 2; ++t) {
        const int iq = i0 + wave * 32 + t * 16 + c;
        const float* qrow = Qbh + (size_t)iq * RS + g * 8;
        #pragma unroll
        for (int f = 0; f < 2; ++f) {
            float4 a  = *(const float4*)(qrow + f * 32);
            float4 bv = *(const float4*)(qrow + f * 32 + 4);
            union { bf16x8 v; unsigned int u[4]; } fr;
            fr.u[0] = pk2(a.x  * SCALE_LOG2E, a.y  * SCALE_LOG2E);
            fr.u[1] = pk2(a.z  * SCALE_LOG2E, a.w  * SCALE_LOG2E);
            fr.u[2] = pk2(bv.x * SCALE_LOG2E, bv.y * SCALE_LOG2E);
            fr.u[3] = pk2(bv.z * SCALE_LOG2E, bv.w * SCALE_LOG2E);
            qf[t][f] = fr.v;
        }
    }

    // Pt addresses (3-bit swizzle, explicit for both write and read) — R5-proven
    unsigned short* pw[4];
    #pragma unroll
    for (int n = 0; n < 4; ++n)
        pw[n] = &Pt[wave][c * 64 + ((((n << 2) | g) ^ sw3) << 2)];
    unsigned short* pr0 = &Pt[wave][c * 64 + (((g << 1) ^ sw3) << 2)];
    unsigned short* pr1 = &Pt[wave][c * 64 + (((8 | (g << 1)) ^ sw3) << 2)];

    // fragment-major image bases: lane's 16B fragment (n,f) of tile jc is at
    // base + jc*2048 + (2n+f)*256 + lane*4  (u32 units)
    const uint32_t* kim = Kimg + (size_t)bh * (NTILE * TILE_U32) + lane * 4;
    const uint32_t* vim = Vimg + (size_t)bh * (NTILE * TILE_U32) + lane * 4;

    f32x4 oacc[2][4];
    #pragma unroll
    for (int t = 0; t < 2; ++t)
        #pragma unroll
        for (int eg = 0; eg < 4; ++eg) oacc[t][eg] = (f32x4){0.f, 0.f, 0.f, 0.f};
    float lsum[2] = {0.f, 0.f};

    for (int jc = 0; jc < NTILE; ++jc) {
        const uint32_t* kg = kim + (size_t)jc * TILE_U32;
        const uint32_t* vg = vim + (size_t)jc * TILE_U32;

        // direct-to-register coalesced fragment loads (16 x dwordx4, no LDS)
        bf16x8 kfr[4][2], vfr[4][2];
        #pragma unroll
        for (int n = 0; n < 4; ++n) {
            kfr[n][0] = *(const bf16x8*)(kg + (n * 2 + 0) * 256);
            kfr[n][1] = *(const bf16x8*)(kg + (n * 2 + 1) * 256);
        }
        #pragma unroll
        for (int eg = 0; eg < 4; ++eg) {
            vfr[eg][0] = *(const bf16x8*)(vg + (eg * 2 + 0) * 256);
            vfr[eg][1] = *(const bf16x8*)(vg + (eg * 2 + 1) * 256);
        }

        // per q-tile: S^T = K*Q^T, p = exp2(s), pack, 4x ds_write_b64
        #pragma unroll
        for (int t = 0; t < 2; ++t) {
            f32x4 sf[4];
            #pragma unroll
            for (int n = 0; n < 4; ++n) {
                f32x4 acc = (f32x4){0.f, 0.f, 0.f, 0.f};
                acc = __builtin_amdgcn_mfma_f32_16x16x32_bf16(kfr[n][0], qf[t][0], acc, 0, 0, 0);
                acc = __builtin_amdgcn_mfma_f32_16x16x32_bf16(kfr[n][1], qf[t][1], acc, 0, 0, 0);
                sf[n] = acc;
            }
            float ls = 0.f;
            #pragma unroll
            for (int n = 0; n < 4; ++n) {
                float p0 = fexp2(sf[n][0]);
                float p1 = fexp2(sf[n][1]);
                float p2 = fexp2(sf[n][2]);
                float p3 = fexp2(sf[n][3]);
                ls += (p0 + p1) + (p2 + p3);
                u32x2 pkd;
                pkd.x = pk2(p0, p1);
                pkd.y = pk2(p2, p3);
                *(u32x2*)(pw[n] + t * 1024) = pkd;
            }
            lsum[t] += ls;
        }
        asm volatile("s_waitcnt lgkmcnt(0)" ::: "memory");  // wave-local Pt drain

        // P B-fragments + V A-fragments -> O^T accumulate
        bf16x8 pfr[2][2];
        #pragma unroll
        for (int t = 0; t < 2; ++t) {
            pfr[t][0] = *(const bf16x8*)(pr0 + t * 1024);
            pfr[t][1] = *(const bf16x8*)(pr1 + t * 1024);
        }
        #pragma unroll
        for (int eg = 0; eg < 4; ++eg) {
            #pragma unroll
            for (int t = 0; t < 2; ++t) {
                oacc[t][eg] = __builtin_amdgcn_mfma_f32_16x16x32_bf16(vfr[eg][0], pfr[t][0], oacc[t][eg], 0, 0, 0);
                oacc[t][eg] = __builtin_amdgcn_mfma_f32_16x16x32_bf16(vfr[eg][1], pfr[t][1], oacc[t][eg], 0, 0, 0);
            }
        }
    }

    // final row-sum reduce across the 4 quads (lanes c, c+16, c+32, c+48)
    float linv[2];
    #pragma unroll
    for (int t = 0; t < 2; ++t) {
        float l = lsum[t];
        l += __shfl_xor(l, 16);
        l += __shfl_xor(l, 32);
        linv[t] = 1.0f / l;
    }

    // local branch scores: j = i-2+jj (fp32, natural-log units).
    // 256 threads x 2 slots cover 128 rows x 4 jj.
    {
        const int br = tid >> 1;
        const int i  = i0 + br;
        const float* qrow = Qbh + (size_t)i * RS;
        #pragma unroll
        for (int halfj = 0; halfj < 2; ++halfj) {
            const int jj = (tid & 1) * 2 + halfj;
            const int j  = i - 2 + jj;
            float s = -INFINITY;
            if (j >= 0 && j < LQ) {
                const float* krow = Kbh + (size_t)j * RS;
                float acc = 0.f;
                #pragma unroll
                for (int e = 0; e < 64; e += 4) {
                    float4 qa = *(const float4*)(qrow + e);
                    float4 ka = *(const float4*)(krow + e);
                    acc = fmaf(qa.x, ka.x, acc); acc = fmaf(qa.y, ka.y, acc);
                    acc = fmaf(qa.z, ka.z, acc); acc = fmaf(qa.w, ka.w, acc);
                }
                s = 0.125f * acc;
            }
            sloc[br][jj] = s;
        }
    }
    __syncthreads();

    // combine global + local, store (O^T: lane holds e=eg*16+g*4+r, q=t*16+c)
    #pragma unroll
    for (int t = 0; t < 2; ++t) {
        const int row = wave * 32 + t * 16 + c;
        const int i   = i0 + row;
        float s0 = sloc[row][0], s1 = sloc[row][1], s2 = sloc[row][2], s3 = sloc[row][3];
        float mx = fmaxf(fmaxf(s0, s1), fmaxf(s2, s3));
        float w0 = expf(s0 - mx), w1 = expf(s1 - mx);
        float w2 = expf(s2 - mx), w3 = expf(s3 - mx);
        float inv = 1.0f / (w0 + w1 + w2 + w3);
        w0 *= inv; w1 *= inv; w2 *= inv; w3 *= inv;
        const float li = linv[t];
        float* orow = Obh + (size_t)i * RS;
        #pragma unroll
        for (int eg = 0; eg < 4; ++eg) {
            const int e0 = eg * 16 + g * 4;
            float v0 = oacc[t][eg][0] * li;
            float v1 = oacc[t][eg][1] * li;
            float v2 = oacc[t][eg][2] * li;
            float v3 = oacc[t][eg][3] * li;
            if (w0 > 0.f) {
                float4 vv = *(const float4*)(Vbh + (size_t)(i - 2) * RS + e0);
                v0 = fmaf(w0, vv.x, v0); v1 = fmaf(w0, vv.y, v1);
                v2 = fmaf(w0, vv.z, v2); v3 = fmaf(w0, vv.w, v3);
            }
            if (w1 > 0.f) {
                float4 vv = *(const float4*)(Vbh + (size_t)(i - 1) * RS + e0);
                v0 = fmaf(w1, vv.x, v0); v1 = fmaf(w1, vv.y, v1);
                v2 = fmaf(w1, vv.z, v2); v3 = fmaf(w1, vv.w, v3);
            }
            {
                float4 vv = *(const float4*)(Vbh + (size_t)i * RS + e0);
                v0 = fmaf(w2, vv.x, v0); v1 = fmaf(w2, vv.y, v1);
                v2 = fmaf(w2, vv.z, v2); v3 = fmaf(w2, vv.w, v3);
            }
            if (w3 > 0.f) {
                float4 vv = *(const float4*)(Vbh + (size_t)(i + 1) * RS + e0);
                v0 = fmaf(w3, vv.x, v0); v1 = fmaf(w3, vv.y, v1);
                v2 = fmaf(w3, vv.z, v2); v3 = fmaf(w3, vv.w, v3);
            }
            float4 outv; outv.x = v0; outv.y = v1; outv.z = v2; outv.w = v3;
            *(float4*)(orow + e0) = outv;
        }
    }
}

// ---- fallback (self-contained, no workspace) ----
__global__ __launch_bounds__(256) void hybrid_attn_fb(
    const float* __restrict__ Q, const float* __restrict__ K,
    const float* __restrict__ V, float* __restrict__ O)
{
    __shared__ unsigned short Ks[64 * 64];
    __shared__ unsigned short Vt[64 * 64];
    __shared__ unsigned short Ps[4][16 * 64];
    __shared__ float sloc[64][4];

    const int tid  = threadIdx.x;
    const int wave = tid >> 6;
    const int lane = tid & 63;
    const int c    = lane & 15;
    const int g    = lane >> 4;
    const int qt   = blockIdx.x;
    const int bh   = blockIdx.y;
    const int b    = bh >> 3;
    const int h    = bh & 7;
    const int i0   = qt * 64;

    const float* Qbh = Q + (size_t)b * LQ * RS + h * EQ;
    const float* Kbh = K + (size_t)b * LQ * RS + h * EQ;
    const float* Vbh = V + (size_t)b * LQ * RS + h * EQ;
    float*       Obh = O + (size_t)b * LQ * RS + h * EQ;

    bf16x8 qf[2];
    {
        const int iA = i0 + wave * 16 + c;
        const float* qrow = Qbh + (size_t)iA * RS + g * 8;
        #pragma unroll
        for (int f = 0; f < 2; ++f) {
            float4 a  = *(const float4*)(qrow + f * 32);
            float4 bv = *(const float4*)(qrow + f * 32 + 4);
            union { bf16x8 v; unsigned int u[4]; } fr;
            fr.u[0] = pk2(a.x  * SCALE_LOG2E, a.y  * SCALE_LOG2E);
            fr.u[1] = pk2(a.z  * SCALE_LOG2E, a.w  * SCALE_LOG2E);
            fr.u[2] = pk2(bv.x * SCALE_LOG2E, bv.y * SCALE_LOG2E);
            fr.u[3] = pk2(bv.z * SCALE_LOG2E, bv.w * SCALE_LOG2E);
            qf[f] = fr.v;
        }
    }

    int kfo[4][2], vfo[4][2], pfo[2], pso[4][4];
    #pragma unroll
    for (int n = 0; n < 4; ++n)
        #pragma unroll
        for (int f = 0; f < 2; ++f)
            kfo[n][f] = (n * 16 + c) * 64 + ((((f << 2) | g) ^ (c & 7)) << 3);
    #pragma unroll
    for (int eg = 0; eg < 4; ++eg)
        #pragma unroll
        for (int kh = 0; kh < 2; ++kh)
            vfo[eg][kh] = (eg * 16 + c) * 64 + ((((kh << 2) | g) ^ (c & 7)) << 3);
    #pragma unroll
    for (int kh = 0; kh < 2; ++kh)
        pfo[kh] = c * 64 + ((((kh << 2) | g) ^ (c & 7)) << 3);
    #pragma unroll
    for (int r = 0; r < 4; ++r) {
        const int row = g * 4 + r;
        #pragma unroll
        for (int n = 0; n < 4; ++n) {
            const int col = n * 16 + c;
            pso[r][n] = row * 64 + ((((col >> 3) ^ (row & 7)) << 3) | (col & 7));
        }
    }

    f32x4 oacc[4];
    #pragma unroll
    for (int eg = 0; eg < 4; ++eg) oacc[eg] = (f32x4){0.f, 0.f, 0.f, 0.f};
    float l_r[4] = {0.f, 0.f, 0.f, 0.f};

    for (int j0 = 0; j0 < LQ; j0 += BN) {
        __syncthreads();
        #pragma unroll
        for (int it = 0; it < 2; ++it) {
            int t2 = tid + it * 256;
            int jr = t2 >> 3, eo = t2 & 7;
            const float* src = Kbh + (size_t)(j0 + jr) * RS + eo * 8;
            float4 a  = *(const float4*)src;
            float4 bv = *(const float4*)(src + 4);
            u32x4 p;
            p.x = pk2(a.x, a.y);   p.y = pk2(a.z, a.w);
            p.z = pk2(bv.x, bv.y); p.w = pk2(bv.z, bv.w);
            *(u32x4*)&Ks[jr * 64 + ((eo ^ (jr & 7)) << 3)] = p;
        }
        #pragma unroll
        for (int it = 0; it < 2; ++it) {
            int t2 = tid + it * 256;
            int e = t2 & 63, jo = t2 >> 6;
            const float* src = Vbh + (size_t)(j0 + jo * 8) * RS + e;
            float v0 = src[0 * RS], v1 = src[1 * RS], v2 = src[2 * RS], v3 = src[3 * RS];
            float v4 = src[4 * RS], v5 = src[5 * RS], v6 = src[6 * RS], v7 = src[7 * RS];
            u32x4 p;
            p.x = pk2(v0, v1); p.y = pk2(v2, v3);
            p.z = pk2(v4, v5); p.w = pk2(v6, v7);
            *(u32x4*)&Vt[e * 64 + ((jo ^ (e & 7)) << 3)] = p;
        }
        __syncthreads();

        f32x4 sf[4];
        #pragma unroll
        for (int n = 0; n < 4; ++n) {
            bf16x8 k0 = *(const bf16x8*)&Ks[kfo[n][0]];
            bf16x8 k1 = *(const bf16x8*)&Ks[kfo[n][1]];
            f32x4 acc = (f32x4){0.f, 0.f, 0.f, 0.f};
            acc = __builtin_amdgcn_mfma_f32_16x16x32_bf16(qf[0], k0, acc, 0, 0, 0);
            acc = __builtin_amdgcn_mfma_f32_16x16x32_bf16(qf[1], k1, acc, 0, 0, 0);
            sf[n] = acc;
        }
        #pragma unroll
        for (int r = 0; r < 4; ++r) {
            float p0 = fexp2(sf[0][r]);
            float p1 = fexp2(sf[1][r]);
            float p2 = fexp2(sf[2][r]);
            float p3 = fexp2(sf[3][r]);
            l_r[r] += (p0 + p1) + (p2 + p3);
            Ps[wave][pso[r][0]] = (unsigned short)f2bf(p0);
            Ps[wave][pso[r][1]] = (unsigned short)f2bf(p1);
            Ps[wave][pso[r][2]] = (unsigned short)f2bf(p2);
            Ps[wave][pso[r][3]] = (unsigned short)f2bf(p3);
        }
        asm volatile("s_waitcnt lgkmcnt(0)" ::: "memory");

        bf16x8 pf0 = *(const bf16x8*)&Ps[wave][pfo[0]];
        bf16x8 pf1 = *(const bf16x8*)&Ps[wave][pfo[1]];
        #pragma unroll
        for (int eg = 0; eg < 4; ++eg) {
            bf16x8 v0 = *(const bf16x8*)&Vt[vfo[eg][0]];
            bf16x8 v1 = *(const bf16x8*)&Vt[vfo[eg][1]];
            oacc[eg] = __builtin_amdgcn_mfma_f32_16x16x32_bf16(pf0, v0, oacc[eg], 0, 0, 0);
            oacc[eg] = __builtin_amdgcn_mfma_f32_16x16x32_bf16(pf1, v1, oacc[eg], 0, 0, 0);
        }
    }

    #pragma unroll
    for (int r = 0; r < 4; ++r) {
        float l = l_r[r];
        l += __shfl_xor(l, 1);
        l += __shfl_xor(l, 2);
        l += __shfl_xor(l, 4);
        l += __shfl_xor(l, 8);
        l_r[r] = 1.0f / l;
    }

    {
        const int br = tid >> 2;
        const int jj = tid & 3;
        const int i  = i0 + br;
        const int j  = i - 2 + jj;
        float s = -INFINITY;
        if (j >= 0 && j < LQ) {
            const float* qrow = Qbh + (size_t)i * RS;
            const float* krow = Kbh + (size_t)j * RS;
            float acc = 0.f;
            #pragma unroll
            for (int e = 0; e < 64; e += 4) {
                float4 qa = *(const float4*)(qrow + e);
                float4 ka = *(const float4*)(krow + e);
                acc = fmaf(qa.x, ka.x, acc); acc = fmaf(qa.y, ka.y, acc);
                acc = fmaf(qa.z, ka.z, acc); acc = fmaf(qa.w, ka.w, acc);
            }
            s = 0.125f * acc;
        }
        sloc[br][jj] = s;
    }
    __syncthreads();

    #pragma unroll
    for (int r = 0; r < 4; ++r) {
        const int row = wave * 16 + g * 4 + r;
        const int i   = i0 + row;
        float s0 = sloc[row][0], s1 = sloc[row][1], s2 = sloc[row][2], s3 = sloc[row][3];
        float mx = fmaxf(fmaxf(s0, s1), fmaxf(s2, s3));
        float w0 = expf(s0 - mx), w1 = expf(s1 - mx);
        float w2 = expf(s2 - mx), w3 = expf(s3 - mx);
        float inv = 1.0f / (w0 + w1 + w2 + w3);
        w0 *= inv; w1 *= inv; w2 *= inv; w3 *= inv;
        const float li = l_r[r];
        float* orow = Obh + (size_t)i * RS;
        #pragma unroll
        for (int eg = 0; eg < 4; ++eg) {
            const int e = eg * 16 + c;
            float val = oacc[eg][r] * li;
            if (w0 > 0.f) val += w0 * Vbh[(size_t)(i - 2) * RS + e];
            if (w1 > 0.f) val += w1 * Vbh[(size_t)(i - 1) * RS + e];
            if (w2 > 0.f) val += w2 * Vbh[(size_t)(i    ) * RS + e];
            if (w3 > 0.f) val += w3 * Vbh[(size_t)(i + 1) * RS + e];
            orow[e] = val;
        }
    }
}

extern "C" void kernel_launch(void* const* d_in, const int* in_sizes, int n_in,
                              void* d_out, int out_size, void* d_ws, size_t ws_size,
                              hipStream_t stream) {
    (void)in_sizes; (void)n_in; (void)out_size;
    const float* Q = (const float*)d_in[0];
    const float* K = (const float*)d_in[1];
    const float* V = (const float*)d_in[2];
    float* O = (float*)d_out;
    const size_t need = (size_t)2 * IMG_U32 * 4;  // 16 MiB
    if (ws_size >= need) {
        uint32_t* Kimg = (uint32_t*)d_ws;
        uint32_t* Vimg = Kimg + IMG_U32;
        hipLaunchKernelGGL(prepack_kernel, dim3(NTILE, BQ * HQ), dim3(256), 0, stream,
                           K, V, Kimg, Vimg);
        hipLaunchKernelGGL(hybrid_attn_v10, dim3((LQ / BMQ) * BQ * HQ), dim3(256), 0, stream,
                           Q, K, V, Kimg, Vimg, O);
    } else {
        hipLaunchKernelGGL(hybrid_attn_fb, dim3(LQ / 64, BQ * HQ), dim3(256), 0, stream,
                           Q, K, V, O);
    }
}